// Round 1
// baseline (79.228 us; speedup 1.0000x reference)
//
#include <hip/hip_runtime.h>

#define NCLS 512
#define DIM 512
#define NTHREADS 256
#define LIST_CAP 2048
#define EPS 1e-6f
#define MARGIN 1.0f

// Kernel 1: per-class row gather + sum.
// One block per class. Scan label array (L2-resident), build LDS index list,
// gather matching rows coalesced (float2/lane), accumulate 2 dims per thread.
__global__ __launch_bounds__(NTHREADS)
void k_class_sums(const float* __restrict__ x, const int* __restrict__ lab,
                  float* __restrict__ cls_sums, int* __restrict__ cls_cnts, int N)
{
    const int c   = blockIdx.x;
    const int tid = threadIdx.x;

    __shared__ int s_list[LIST_CAP];
    __shared__ int s_cnt;
    if (tid == 0) s_cnt = 0;
    __syncthreads();

    float2 acc = make_float2(0.f, 0.f);
    int my_total = 0;

    const int4* lab4 = (const int4*)lab;
    const int nv = N >> 2;  // int4 elements
    const float2* x2 = (const float2*)x;

    for (int base = 0; base < nv; base += NTHREADS) {
        const int j = base + tid;
        if (j < nv) {
            int4 l = lab4[j];
            int i0 = j << 2;
            if (l.x == c) s_list[atomicAdd(&s_cnt, 1)] = i0;
            if (l.y == c) s_list[atomicAdd(&s_cnt, 1)] = i0 + 1;
            if (l.z == c) s_list[atomicAdd(&s_cnt, 1)] = i0 + 2;
            if (l.w == c) s_list[atomicAdd(&s_cnt, 1)] = i0 + 3;
        }
        __syncthreads();
        const int cnt = s_cnt;          // uniform snapshot
        __syncthreads();                // no appends until all have read
        if (cnt > LIST_CAP - 4 * NTHREADS) {
            // drain list (uniform branch)
            int r = 0;
            for (; r + 4 <= cnt; r += 4) {
                int r0 = s_list[r], r1 = s_list[r + 1], r2 = s_list[r + 2], r3 = s_list[r + 3];
                float2 v0 = x2[(size_t)r0 * (DIM / 2) + tid];
                float2 v1 = x2[(size_t)r1 * (DIM / 2) + tid];
                float2 v2 = x2[(size_t)r2 * (DIM / 2) + tid];
                float2 v3 = x2[(size_t)r3 * (DIM / 2) + tid];
                acc.x += v0.x + v1.x + v2.x + v3.x;
                acc.y += v0.y + v1.y + v2.y + v3.y;
            }
            for (; r < cnt; ++r) {
                float2 v = x2[(size_t)s_list[r] * (DIM / 2) + tid];
                acc.x += v.x; acc.y += v.y;
            }
            my_total += cnt;
            __syncthreads();
            if (tid == 0) s_cnt = 0;
            __syncthreads();
        }
    }

    // final drain
    {
        const int cnt = s_cnt;
        int r = 0;
        for (; r + 4 <= cnt; r += 4) {
            int r0 = s_list[r], r1 = s_list[r + 1], r2 = s_list[r + 2], r3 = s_list[r + 3];
            float2 v0 = x2[(size_t)r0 * (DIM / 2) + tid];
            float2 v1 = x2[(size_t)r1 * (DIM / 2) + tid];
            float2 v2 = x2[(size_t)r2 * (DIM / 2) + tid];
            float2 v3 = x2[(size_t)r3 * (DIM / 2) + tid];
            acc.x += v0.x + v1.x + v2.x + v3.x;
            acc.y += v0.y + v1.y + v2.y + v3.y;
        }
        for (; r < cnt; ++r) {
            float2 v = x2[(size_t)s_list[r] * (DIM / 2) + tid];
            acc.x += v.x; acc.y += v.y;
        }
        my_total += cnt;
    }

    ((float2*)cls_sums)[c * (DIM / 2) + tid] = acc;
    if (tid == 0) cls_cnts[c] = my_total;
}

// Kernel 2: total[d] = sum over classes of cls_sums[c][d]; zero the output.
__global__ __launch_bounds__(DIM)
void k_total(const float* __restrict__ cls_sums, float* __restrict__ total,
             float* __restrict__ d_out)
{
    const int d = threadIdx.x;
    float s0 = 0.f, s1 = 0.f, s2 = 0.f, s3 = 0.f;
    for (int c = 0; c < NCLS; c += 4) {
        s0 += cls_sums[(size_t)(c + 0) * DIM + d];
        s1 += cls_sums[(size_t)(c + 1) * DIM + d];
        s2 += cls_sums[(size_t)(c + 2) * DIM + d];
        s3 += cls_sums[(size_t)(c + 3) * DIM + d];
    }
    total[d] = (s0 + s1) + (s2 + s3);
    if (d == 0) d_out[0] = 0.f;
}

// Kernel 3: per class, d_c = ||s/c - (total-s)/(N-c) + eps||_2;
// loss += cnt * max(1-d,0)^2 / N.
__global__ __launch_bounds__(NTHREADS)
void k_finalize(const float* __restrict__ cls_sums, const int* __restrict__ cls_cnts,
                const float* __restrict__ total, float* __restrict__ d_out, int N)
{
    const int c   = blockIdx.x;
    const int tid = threadIdx.x;
    const int cnt = cls_cnts[c];

    float2 s = ((const float2*)cls_sums)[c * (DIM / 2) + tid];
    float2 t = ((const float2*)total)[tid];

    float ss = 0.f;
    if (cnt > 0) {
        float inv_c  = 1.f / (float)cnt;
        float inv_nc = 1.f / (float)(N - cnt);
        float d0 = s.x * inv_c - (t.x - s.x) * inv_nc + EPS;
        float d1 = s.y * inv_c - (t.y - s.y) * inv_nc + EPS;
        ss = d0 * d0 + d1 * d1;
    }

    // reduce across 256 threads: 64-lane wave shuffle, then LDS across 4 waves
    #pragma unroll
    for (int o = 1; o < 64; o <<= 1) ss += __shfl_xor(ss, o, 64);

    __shared__ float s_red[NTHREADS / 64];
    if ((tid & 63) == 0) s_red[tid >> 6] = ss;
    __syncthreads();

    if (tid == 0) {
        float tot = (s_red[0] + s_red[1]) + (s_red[2] + s_red[3]);
        float d = sqrtf(tot);
        float w = fmaxf(MARGIN - d, 0.f);
        float contrib = (float)cnt * w * w / (float)N;
        if (cnt > 0) atomicAdd(d_out, contrib);
    }
}

extern "C" void kernel_launch(void* const* d_in, const int* in_sizes, int n_in,
                              void* d_out, int out_size, void* d_ws, size_t ws_size,
                              hipStream_t stream)
{
    const float* x   = (const float*)d_in[0];
    const int*   lab = (const int*)d_in[1];
    float*       out = (float*)d_out;

    const int N = in_sizes[1];  // 65536 samples (labels); in_sizes[0] == N*DIM

    float* cls_sums = (float*)d_ws;                    // NCLS*DIM f32 = 1 MiB
    float* total    = cls_sums + (size_t)NCLS * DIM;   // DIM f32
    int*   cls_cnts = (int*)(total + DIM);             // NCLS int

    k_class_sums<<<NCLS, NTHREADS, 0, stream>>>(x, lab, cls_sums, cls_cnts, N);
    k_total<<<1, DIM, 0, stream>>>(cls_sums, total, out);
    k_finalize<<<NCLS, NTHREADS, 0, stream>>>(cls_sums, cls_cnts, total, out, N);
}